// Round 4
// baseline (635.445 us; speedup 1.0000x reference)
//
#include <hip/hip_runtime.h>
#include <math.h>

#define BSZ 128
#define NN_ 4096
#define MM_ 64
#define HH_ 512
#define HALFN 2048
#define EPSF 1e-8f

__device__ __forceinline__ float sigmoidf_(float x) { return 1.0f / (1.0f + expf(-x)); }
__device__ __forceinline__ float softplusf_(float x) { return fmaxf(x, 0.0f) + log1pf(expf(-fabsf(x))); }

__device__ __forceinline__ void agstf(float* p, float v) {
    __hip_atomic_store(p, v, __ATOMIC_RELAXED, __HIP_MEMORY_SCOPE_AGENT);
}
__device__ __forceinline__ float agldf(const float* p) {
    return __hip_atomic_load(p, __ATOMIC_RELAXED, __HIP_MEMORY_SCOPE_AGENT);
}

// ------------------------------------------------------------------
// gatesP[z][128,2048] = [in_data|prev_reads|h_prev][128,1024] @ [W_ih|W_hh][2048,1024]^T
// split-K=4 into separate partial buffers (NO atomics, no zero-init)
__global__ __launch_bounds__(256) void k_gemm_gates(const float* __restrict__ in_data,
                                                    const float* __restrict__ prev_reads,
                                                    const float* __restrict__ h_prev,
                                                    const float* __restrict__ W_ih,
                                                    const float* __restrict__ W_hh,
                                                    float* __restrict__ Cp) {
    __shared__ float Alds[64 * 65];
    __shared__ float Wlds[64 * 65];
    int t = threadIdx.x;
    int n0 = blockIdx.x * 64;
    int b0 = blockIdx.y * 64;
    float* C = Cp + (size_t)blockIdx.z * (BSZ * 2048);
    int ob = (t & 15) * 4;
    int bb = (t >> 4) * 4;
    float acc[4][4];
#pragma unroll
    for (int i = 0; i < 4; ++i)
#pragma unroll
        for (int j = 0; j < 4; ++j) acc[i][j] = 0.f;
    for (int kt = 0; kt < 4; ++kt) {
        int k0 = blockIdx.z * 256 + kt * 64;
        __syncthreads();
        for (int i = 0; i < 4; ++i) {
            int f = t + 256 * i;
            int row = f >> 4, kk = (f & 15) * 4;
            int k = k0 + kk;
            float4 v;
            if (k < 256) v = *(const float4*)(in_data + ((b0 + row) << 8) + k);
            else if (k < 512) {
                int q = k - 256;
                v = *(const float4*)(prev_reads + (((q >> 6) * BSZ + b0 + row) << 6) + (q & 63));
            } else v = *(const float4*)(h_prev + ((b0 + row) << 9) + (k - 512));
            Alds[(kk + 0) * 65 + row] = v.x;
            Alds[(kk + 1) * 65 + row] = v.y;
            Alds[(kk + 2) * 65 + row] = v.z;
            Alds[(kk + 3) * 65 + row] = v.w;
        }
        for (int i = 0; i < 4; ++i) {
            int f = t + 256 * i;
            int o = f >> 4, kk = (f & 15) * 4;
            int j = n0 + o, k = k0 + kk;
            const float* src = (k < 512) ? (W_ih + (size_t)j * 512 + k)
                                         : (W_hh + (size_t)j * 512 + (k - 512));
            float4 v = *(const float4*)src;
            Wlds[(kk + 0) * 65 + o] = v.x;
            Wlds[(kk + 1) * 65 + o] = v.y;
            Wlds[(kk + 2) * 65 + o] = v.z;
            Wlds[(kk + 3) * 65 + o] = v.w;
        }
        __syncthreads();
        for (int kk = 0; kk < 64; ++kk) {
            const float* wp = &Wlds[kk * 65 + ob];
            const float* ap = &Alds[kk * 65 + bb];
            float w0 = wp[0], w1 = wp[1], w2 = wp[2], w3 = wp[3];
#pragma unroll
            for (int j = 0; j < 4; ++j) {
                float av = ap[j];
                acc[0][j] = fmaf(w0, av, acc[0][j]);
                acc[1][j] = fmaf(w1, av, acc[1][j]);
                acc[2][j] = fmaf(w2, av, acc[2][j]);
                acc[3][j] = fmaf(w3, av, acc[3][j]);
            }
        }
    }
#pragma unroll
    for (int i = 0; i < 4; ++i)
#pragma unroll
        for (int j = 0; j < 4; ++j)
            C[(size_t)(b0 + bb + j) * 2048 + n0 + ob + i] = acc[i][j];
}

// ------------------------------------------------------------------
// LSTM pointwise, summing the 4 gate partials
__global__ void k_lstm(const float* __restrict__ gatesP, const float* __restrict__ b_ih,
                       const float* __restrict__ b_hh, const float* __restrict__ c_prev,
                       float* __restrict__ cbuf, float* __restrict__ hbuf) {
    int idx = blockIdx.x * blockDim.x + threadIdx.x;
    if (idx >= BSZ * HH_) return;
    int b = idx >> 9, j = idx & 511;
    float gi = b_ih[j]        + b_hh[j];
    float gf = b_ih[512 + j]  + b_hh[512 + j];
    float gg = b_ih[1024 + j] + b_hh[1024 + j];
    float go = b_ih[1536 + j] + b_hh[1536 + j];
#pragma unroll
    for (int p = 0; p < 4; ++p) {
        const float* gr = gatesP + (size_t)p * (BSZ * 2048) + (size_t)b * 2048;
        gi += gr[j];
        gf += gr[512 + j];
        gg += gr[1024 + j];
        go += gr[1536 + j];
    }
    float cc = sigmoidf_(gf) * c_prev[idx] + sigmoidf_(gi) * tanhf(gg);
    float hh = sigmoidf_(go) * tanhf(cc);
    cbuf[idx] = cc;
    hbuf[idx] = hh;
}

// ------------------------------------------------------------------
__device__ __forceinline__ const float* whead_row_ptr(const float* Wk, const float* Wbeta,
                                                      const float* Wg, const float* Ws,
                                                      const float* Wgam, const float* We,
                                                      const float* Wa, int r) {
    int i = r / 198, q = r - i * 198;
    if (q < 64)  return Wk + (size_t)((i << 6) + q) * 512;
    if (q == 64) return Wbeta + (size_t)i * 512;
    if (q == 65) return Wg + (size_t)i * 512;
    if (q <= 68) return Ws + (size_t)(i * 3 + q - 66) * 512;
    if (q == 69) return Wgam + (size_t)i * 512;
    if (q < 134) return We + (size_t)((i << 6) + q - 70) * 512;
    return Wa + (size_t)((i << 6) + q - 134) * 512;
}

__global__ __launch_bounds__(256) void k_gemm_head(const float* __restrict__ A,
                                                   const float* __restrict__ Wk,
                                                   const float* __restrict__ Wbeta,
                                                   const float* __restrict__ Wg,
                                                   const float* __restrict__ Ws,
                                                   const float* __restrict__ Wgam,
                                                   const float* __restrict__ We,
                                                   const float* __restrict__ Wa,
                                                   float* __restrict__ Cp) {
    __shared__ float Alds[64 * 65];
    __shared__ float Wlds[64 * 65];
    int t = threadIdx.x;
    int n0 = blockIdx.x * 64;
    int b0 = blockIdx.y * 64;
    float* C = Cp + (size_t)blockIdx.z * (BSZ * 1408);
    int ob = (t & 15) * 4;
    int bb = (t >> 4) * 4;
    float acc[4][4];
#pragma unroll
    for (int i = 0; i < 4; ++i)
#pragma unroll
        for (int j = 0; j < 4; ++j) acc[i][j] = 0.f;
    for (int kt = 0; kt < 4; ++kt) {
        int k0 = blockIdx.z * 256 + kt * 64;
        __syncthreads();
        for (int i = 0; i < 4; ++i) {
            int f = t + 256 * i;
            int row = f >> 4, kk = (f & 15) * 4;
            float4 v = *(const float4*)(A + (size_t)(b0 + row) * 512 + k0 + kk);
            Alds[(kk + 0) * 65 + row] = v.x;
            Alds[(kk + 1) * 65 + row] = v.y;
            Alds[(kk + 2) * 65 + row] = v.z;
            Alds[(kk + 3) * 65 + row] = v.w;
        }
        for (int i = 0; i < 4; ++i) {
            int f = t + 256 * i;
            int o = f >> 4, kk = (f & 15) * 4;
            int r = n0 + o;
            float4 v = make_float4(0.f, 0.f, 0.f, 0.f);
            if (r < 1386) {
                const float* p = whead_row_ptr(Wk, Wbeta, Wg, Ws, Wgam, We, Wa, r) + k0 + kk;
                v = *(const float4*)p;
            }
            Wlds[(kk + 0) * 65 + o] = v.x;
            Wlds[(kk + 1) * 65 + o] = v.y;
            Wlds[(kk + 2) * 65 + o] = v.z;
            Wlds[(kk + 3) * 65 + o] = v.w;
        }
        __syncthreads();
        for (int kk = 0; kk < 64; ++kk) {
            const float* wp = &Wlds[kk * 65 + ob];
            const float* ap = &Alds[kk * 65 + bb];
            float w0 = wp[0], w1 = wp[1], w2 = wp[2], w3 = wp[3];
#pragma unroll
            for (int j = 0; j < 4; ++j) {
                float av = ap[j];
                acc[0][j] = fmaf(w0, av, acc[0][j]);
                acc[1][j] = fmaf(w1, av, acc[1][j]);
                acc[2][j] = fmaf(w2, av, acc[2][j]);
                acc[3][j] = fmaf(w3, av, acc[3][j]);
            }
        }
    }
#pragma unroll
    for (int i = 0; i < 4; ++i)
#pragma unroll
        for (int j = 0; j < 4; ++j)
            C[(size_t)(b0 + bb + j) * 1408 + n0 + ob + i] = acc[i][j];
}

// ------------------------------------------------------------------
// per (head<7, b): sum 2 partials + bias + activations
__global__ __launch_bounds__(256) void k_headact(const float* __restrict__ C0,
                                                 const float* __restrict__ C1,
                                                 const float* __restrict__ bk, const float* __restrict__ bbeta,
                                                 const float* __restrict__ bg, const float* __restrict__ bs,
                                                 const float* __restrict__ bgam, const float* __restrict__ be,
                                                 const float* __restrict__ ba,
                                                 float* __restrict__ keys, float* __restrict__ knorm,
                                                 float* __restrict__ betaA, float* __restrict__ gA,
                                                 float* __restrict__ gammaA, float* __restrict__ sA,
                                                 float* __restrict__ eA, float* __restrict__ aA) {
    __shared__ float sk[64];
    __shared__ float s3[3];
    int blk = blockIdx.x;
    int i = blk >> 7, b = blk & 127;
    int q = threadIdx.x;
    float val = 0.f;
    if (q < 198) {
        float bv = (q < 64)   ? bk[(i << 6) + q]
                 : (q == 64)  ? bbeta[i]
                 : (q == 65)  ? bg[i]
                 : (q <= 68)  ? bs[i * 3 + q - 66]
                 : (q == 69)  ? bgam[i]
                 : (q < 134)  ? be[(i << 6) + q - 70]
                              : ba[(i << 6) + q - 134];
        size_t idx = (size_t)b * 1408 + i * 198 + q;
        val = C0[idx] + C1[idx] + bv;
    }
    if (q < 64) { keys[(size_t)(i * BSZ + b) * 64 + q] = val; sk[q] = val * val; }
    if (q >= 66 && q <= 68) s3[q - 66] = val;
    __syncthreads();
    if (q == 0) {
        float s = 0.f;
        for (int m2 = 0; m2 < 64; ++m2) s += sk[m2];
        knorm[i * BSZ + b] = sqrtf(s);
    }
    if (q == 64) betaA[i * BSZ + b] = softplusf_(val);
    if (q == 65) gA[i * BSZ + b] = sigmoidf_(val);
    if (q == 69) gammaA[i * BSZ + b] = 1.f + softplusf_(val);
    if (q == 66) {
        float mx = fmaxf(s3[0], fmaxf(s3[1], s3[2]));
        float e0 = expf(s3[0] - mx), e1 = expf(s3[1] - mx), e2 = expf(s3[2] - mx);
        float inv = 1.f / (e0 + e1 + e2);
        sA[(i * BSZ + b) * 3 + 0] = e0 * inv;
        sA[(i * BSZ + b) * 3 + 1] = e1 * inv;
        sA[(i * BSZ + b) * 3 + 2] = e2 * inv;
    }
    if (q >= 70 && q < 134)  eA[(size_t)(i * BSZ + b) * 64 + (q - 70)] = sigmoidf_(val);
    if (q >= 134 && q < 198) aA[(size_t)(i * BSZ + b) * 64 + (q - 134)] = tanhf(val);
}

// ------------------------------------------------------------------
// Persistent per-batch-half midchain: 256 blocks (b = bid&127, half = bid>>7).
// Each block owns rows [half*2048, half*2048+2048) of batch b for ALL 5 sweeps;
// w1/w3/w5 + rotating read-weight + sim-exp live in LDS. Softmax is max-free
// (|beta*sim| <= ~10), so normalizers are additive across the two halves and
// exchanged via agent-scope acquire/release flag slots (8 tiny exchanges).
__global__ __launch_bounds__(512) void k_mega(const float* __restrict__ mem,
                                              const float* __restrict__ prev_w,
                                              const float* __restrict__ eA, const float* __restrict__ aA,
                                              const float* __restrict__ keys, const float* __restrict__ knorm,
                                              const float* __restrict__ betaA, const float* __restrict__ gA,
                                              const float* __restrict__ gammaA, const float* __restrict__ sA,
                                              float* __restrict__ r_out,
                                              float* __restrict__ xpay, int* __restrict__ xflag) {
    __shared__ float w1s[HALFN], w3s[HALFN], w5s[HALFN], wrs[HALFN];
    __shared__ float sxp[2][HALFN];           // sim-exp, overlaid in-place by wg
    __shared__ __align__(16) float rred[32][64];
    __shared__ float xch[8];
    __shared__ float redu[16];

    int bid = blockIdx.x;
    int b = bid & 127;
    int half = bid >> 7;                       // pair (b, b+128): same XCD under rr dispatch
    int t = threadIdx.x;
    int lane = t & 15, grp = t >> 4;           // 32 row-groups of 16 lanes
    int m4 = lane * 4;
    int wv = t >> 6, ln = t & 63;
    const int n0g = half * HALFN;
    const int ph = 1 - half;

    float4 e1 = *(const float4*)(eA + (size_t)(1 * BSZ + b) * 64 + m4);
    float4 a1 = *(const float4*)(aA + (size_t)(1 * BSZ + b) * 64 + m4);
    float4 e3 = *(const float4*)(eA + (size_t)(3 * BSZ + b) * 64 + m4);
    float4 a3 = *(const float4*)(aA + (size_t)(3 * BSZ + b) * 64 + m4);
    float4 e5 = *(const float4*)(eA + (size_t)(5 * BSZ + b) * 64 + m4);
    float4 a5 = *(const float4*)(aA + (size_t)(5 * BSZ + b) * 64 + m4);

    int* myflag = xflag + (b * 2 + half) * 8;
    int* pflag  = xflag + (b * 2 + ph) * 8;
    float* mypay = xpay + (size_t)(b * 2 + half) * 64;
    const float* ppay = xpay + (size_t)(b * 2 + ph) * 64;

    const float* membase = mem + ((size_t)b * 4096 + n0g) * 64;

    const int napplyA[5] = {0, 1, 2, 3, 3};
    const int nsimsA[5]  = {2, 2, 2, 1, 0};
    const int rstateA[5] = {-1, 0, 1, 2, 3};

    for (int p = 0; p < 5; ++p) {
        int napply = napplyA[p], nsims = nsimsA[p], rstate = rstateA[p];
        bool doread = (p >= 1);
        float bet0 = 0.f, bet1 = 0.f, kn0 = 0.f, kn1 = 0.f;
        float4 k0v = make_float4(0.f, 0.f, 0.f, 0.f), k1v = k0v;
        if (nsims > 0) {
            int hh = 2 * p;
            bet0 = betaA[hh * BSZ + b];
            k0v = *(const float4*)(keys + (size_t)(hh * BSZ + b) * 64 + m4);
            kn0 = knorm[hh * BSZ + b];
        }
        if (nsims > 1) {
            int hh = 2 * p + 1;
            bet1 = betaA[hh * BSZ + b];
            k1v = *(const float4*)(keys + (size_t)(hh * BSZ + b) * 64 + m4);
            kn1 = knorm[hh * BSZ + b];
        }
        float4 racc = make_float4(0.f, 0.f, 0.f, 0.f);
        for (int rc = 0; rc < 64; ++rc) {
            int nl = rc * 32 + grp;
            float4 m = *(const float4*)(membase + (size_t)nl * 64 + m4);
            float4 mr = m;
            if (napply >= 1) {
                float w = w1s[nl];
                m.x = m.x * (1.f - w * e1.x) + w * a1.x;
                m.y = m.y * (1.f - w * e1.y) + w * a1.y;
                m.z = m.z * (1.f - w * e1.z) + w * a1.z;
                m.w = m.w * (1.f - w * e1.w) + w * a1.w;
                if (rstate == 1) mr = m;
            }
            if (napply >= 2) {
                float w = w3s[nl];
                m.x = m.x * (1.f - w * e3.x) + w * a3.x;
                m.y = m.y * (1.f - w * e3.y) + w * a3.y;
                m.z = m.z * (1.f - w * e3.z) + w * a3.z;
                m.w = m.w * (1.f - w * e3.w) + w * a3.w;
                if (rstate == 2) mr = m;
            }
            if (napply >= 3) {
                float w = w5s[nl];
                m.x = m.x * (1.f - w * e5.x) + w * a5.x;
                m.y = m.y * (1.f - w * e5.y) + w * a5.y;
                m.z = m.z * (1.f - w * e5.z) + w * a5.z;
                m.w = m.w * (1.f - w * e5.w) + w * a5.w;
                if (rstate == 3) mr = m;
            }
            if (doread) {
                float wr = wrs[nl];
                racc.x = fmaf(wr, mr.x, racc.x);
                racc.y = fmaf(wr, mr.y, racc.y);
                racc.z = fmaf(wr, mr.z, racc.z);
                racc.w = fmaf(wr, mr.w, racc.w);
            }
            if (nsims > 0) {
                float d0 = m.x * k0v.x + m.y * k0v.y + m.z * k0v.z + m.w * k0v.w;
                float nn = m.x * m.x + m.y * m.y + m.z * m.z + m.w * m.w;
                float d1 = 0.f;
                if (nsims > 1) d1 = m.x * k1v.x + m.y * k1v.y + m.z * k1v.z + m.w * k1v.w;
#pragma unroll
                for (int off = 8; off >= 1; off >>= 1) {
                    d0 += __shfl_xor(d0, off, 16);
                    nn += __shfl_xor(nn, off, 16);
                    if (nsims > 1) d1 += __shfl_xor(d1, off, 16);
                }
                if (lane == 0) {
                    float nm = sqrtf(nn);
                    sxp[0][nl] = expf(bet0 * (d0 / (nm * kn0 + EPSF)));
                    if (nsims > 1) sxp[1][nl] = expf(bet1 * (d1 / (nm * kn1 + EPSF)));
                }
            }
        }
        if (doread) {
            *(float4*)(&rred[grp][m4]) = racc;
            __syncthreads();
            if (t < 64) {
                float s = 0.f;
#pragma unroll
                for (int g2 = 0; g2 < 32; ++g2) s += rred[g2][t];
                atomicAdd(&r_out[(size_t)((p - 1) * BSZ + b) * 64 + t], s);
            }
        }
        __syncthreads();
        if (p == 4) break;

        // ---------- weights phase for heads h0=2p (read->wrs), h1=2p+1 ----------
        int h0 = 2 * p, h1 = 2 * p + 1;
        int nheads = (p < 3) ? 2 : 1;
        int se = 2 * p, so = 2 * p + 1;
        // partial exp-sums
        float p0 = 0.f, p1 = 0.f;
#pragma unroll
        for (int j = 0; j < 4; ++j) {
            int n = t + 512 * j;
            p0 += sxp[0][n];
            if (nheads > 1) p1 += sxp[1][n];
        }
#pragma unroll
        for (int off = 32; off >= 1; off >>= 1) {
            p0 += __shfl_xor(p0, off);
            p1 += __shfl_xor(p1, off);
        }
        if (ln == 0) { redu[wv] = p0; redu[8 + wv] = p1; }
        __syncthreads();
        if (t == 0) {
            float P0 = 0.f, P1 = 0.f;
#pragma unroll
            for (int w = 0; w < 8; ++w) { P0 += redu[w]; P1 += redu[8 + w]; }
            float* mp = mypay + se * 8;
            agstf(mp + 0, P0);
            agstf(mp + 1, sxp[0][0]);
            agstf(mp + 2, sxp[0][HALFN - 1]);
            agstf(mp + 3, P1);
            agstf(mp + 4, (nheads > 1) ? sxp[1][0] : 0.f);
            agstf(mp + 5, (nheads > 1) ? sxp[1][HALFN - 1] : 0.f);
            __hip_atomic_store(&myflag[se], 1, __ATOMIC_RELEASE, __HIP_MEMORY_SCOPE_AGENT);
            int spins = 0;
            while (__hip_atomic_load(&pflag[se], __ATOMIC_ACQUIRE, __HIP_MEMORY_SCOPE_AGENT) == 0) {
                __builtin_amdgcn_s_sleep(2);
                if (++spins > (1 << 26)) break;   // anti-hang guard
            }
            const float* pp = ppay + se * 8;
            float q0 = agldf(pp + 0), ef0 = agldf(pp + 1), el0 = agldf(pp + 2);
            float q1 = agldf(pp + 3), ef1 = agldf(pp + 4), el1 = agldf(pp + 5);
            float invS0 = 1.f / (P0 + q0);
            float invS1 = (nheads > 1) ? 1.f / (P1 + q1) : 0.f;
            float g0v = gA[h0 * BSZ + b];
            size_t base0 = (size_t)(h0 * BSZ + b) * 4096;
            xch[0] = invS0;
            xch[1] = invS1;
            xch[2] = g0v * el0 * invS0 + (1.f - g0v) * prev_w[base0 + ph * HALFN + HALFN - 1]; // left of nl=0
            xch[3] = g0v * ef0 * invS0 + (1.f - g0v) * prev_w[base0 + ph * HALFN];            // right of nl=2047
            if (nheads > 1) {
                float g1v = gA[h1 * BSZ + b];
                size_t base1 = (size_t)(h1 * BSZ + b) * 4096;
                xch[4] = g1v * el1 * invS1 + (1.f - g1v) * prev_w[base1 + ph * HALFN + HALFN - 1];
                xch[5] = g1v * ef1 * invS1 + (1.f - g1v) * prev_w[base1 + ph * HALFN];
            }
        }
        __syncthreads();
        float invS0 = xch[0], invS1 = xch[1];
        float bL0 = xch[2], bR0 = xch[3], bL1 = xch[4], bR1 = xch[5];
        // head0 wg in-place
        float g0v = gA[h0 * BSZ + b], gam0 = gammaA[h0 * BSZ + b];
        float s00 = sA[(h0 * BSZ + b) * 3 + 0], s01 = sA[(h0 * BSZ + b) * 3 + 1], s02 = sA[(h0 * BSZ + b) * 3 + 2];
        const float* pw0 = prev_w + (size_t)(h0 * BSZ + b) * 4096 + n0g;
#pragma unroll
        for (int j = 0; j < 4; ++j) {
            int n = t + 512 * j;
            sxp[0][n] = g0v * sxp[0][n] * invS0 + (1.f - g0v) * pw0[n];
        }
        __syncthreads();
        float tv0[4];
        float lp0 = 0.f;
#pragma unroll
        for (int j = 0; j < 4; ++j) {
            int n = t + 512 * j;
            float left = (n == 0) ? bL0 : sxp[0][n - 1];
            float right = (n == HALFN - 1) ? bR0 : sxp[0][n + 1];
            float wsft = s00 * right + s01 * sxp[0][n] + s02 * left;
            float wp = powf(wsft, gam0);
            tv0[j] = wp;
            lp0 += wp;
        }
        float tv1[4] = {0.f, 0.f, 0.f, 0.f};
        float lp1 = 0.f;
        if (nheads > 1) {
            float g1v = gA[h1 * BSZ + b], gam1 = gammaA[h1 * BSZ + b];
            float s10 = sA[(h1 * BSZ + b) * 3 + 0], s11 = sA[(h1 * BSZ + b) * 3 + 1], s12 = sA[(h1 * BSZ + b) * 3 + 2];
            const float* pw1 = prev_w + (size_t)(h1 * BSZ + b) * 4096 + n0g;
#pragma unroll
            for (int j = 0; j < 4; ++j) {
                int n = t + 512 * j;
                sxp[1][n] = g1v * sxp[1][n] * invS1 + (1.f - g1v) * pw1[n];
            }
            __syncthreads();
#pragma unroll
            for (int j = 0; j < 4; ++j) {
                int n = t + 512 * j;
                float left = (n == 0) ? bL1 : sxp[1][n - 1];
                float right = (n == HALFN - 1) ? bR1 : sxp[1][n + 1];
                float wsft = s10 * right + s11 * sxp[1][n] + s12 * left;
                float wp = powf(wsft, gam1);
                tv1[j] = wp;
                lp1 += wp;
            }
        }
#pragma unroll
        for (int off = 32; off >= 1; off >>= 1) {
            lp0 += __shfl_xor(lp0, off);
            lp1 += __shfl_xor(lp1, off);
        }
        if (ln == 0) { redu[wv] = lp0; redu[8 + wv] = lp1; }
        __syncthreads();
        if (t == 0) {
            float S0 = 0.f, S1 = 0.f;
#pragma unroll
            for (int w = 0; w < 8; ++w) { S0 += redu[w]; S1 += redu[8 + w]; }
            float* mp = mypay + so * 8;
            agstf(mp + 0, S0);
            agstf(mp + 1, S1);
            __hip_atomic_store(&myflag[so], 1, __ATOMIC_RELEASE, __HIP_MEMORY_SCOPE_AGENT);
            int spins = 0;
            while (__hip_atomic_load(&pflag[so], __ATOMIC_ACQUIRE, __HIP_MEMORY_SCOPE_AGENT) == 0) {
                __builtin_amdgcn_s_sleep(2);
                if (++spins > (1 << 26)) break;
            }
            float r0 = agldf(ppay + so * 8 + 0);
            float r1 = agldf(ppay + so * 8 + 1);
            xch[0] = 1.f / (S0 + r0 + EPSF);
            xch[1] = (nheads > 1) ? 1.f / (S1 + r1 + EPSF) : 0.f;
        }
        __syncthreads();
        float inv20 = xch[0], inv21 = xch[1];
        float* slot1 = (p == 0) ? w1s : (p == 1) ? w3s : w5s;
#pragma unroll
        for (int j = 0; j < 4; ++j) {
            int n = t + 512 * j;
            wrs[n] = tv0[j] * inv20;           // even head = read head -> rotating slot
            if (nheads > 1) slot1[n] = tv1[j] * inv21;
        }
        __syncthreads();
    }
}

// ------------------------------------------------------------------
// out[128,256] = sigmoid([hbuf|rbuf][128,768] @ W_out[256,768]^T + b_out)
__global__ __launch_bounds__(256) void k_out_full(const float* __restrict__ hbuf,
                                                  const float* __restrict__ rbuf,
                                                  const float* __restrict__ W_out,
                                                  const float* __restrict__ b_out,
                                                  float* __restrict__ out) {
    __shared__ float Alds[64 * 65];
    __shared__ float Wlds[64 * 65];
    int t = threadIdx.x;
    int n0 = blockIdx.x * 64;
    int b0 = blockIdx.y * 64;
    int ob = (t & 15) * 4;
    int bb = (t >> 4) * 4;
    float acc[4][4];
#pragma unroll
    for (int i = 0; i < 4; ++i)
#pragma unroll
        for (int j = 0; j < 4; ++j) acc[i][j] = 0.f;
    for (int k0 = 0; k0 < 768; k0 += 64) {
        __syncthreads();
        for (int i = 0; i < 4; ++i) {
            int f = t + 256 * i;
            int rb = f >> 4, kk = (f & 15) * 4;
            int k = k0 + kk;
            float4 v;
            if (k < 512) v = *(const float4*)(hbuf + ((b0 + rb) << 9) + k);
            else {
                int q = k - 512;
                v = *(const float4*)(rbuf + (((q >> 6) * BSZ + b0 + rb) << 6) + (q & 63));
            }
            Alds[(kk + 0) * 65 + rb] = v.x;
            Alds[(kk + 1) * 65 + rb] = v.y;
            Alds[(kk + 2) * 65 + rb] = v.z;
            Alds[(kk + 3) * 65 + rb] = v.w;
        }
        for (int i = 0; i < 4; ++i) {
            int f = t + 256 * i;
            int o = f >> 4, kk = (f & 15) * 4;
            float4 v = *(const float4*)(W_out + (size_t)(n0 + o) * 768 + k0 + kk);
            Wlds[(kk + 0) * 65 + o] = v.x;
            Wlds[(kk + 1) * 65 + o] = v.y;
            Wlds[(kk + 2) * 65 + o] = v.z;
            Wlds[(kk + 3) * 65 + o] = v.w;
        }
        __syncthreads();
        for (int kk = 0; kk < 64; ++kk) {
            const float* wp = &Wlds[kk * 65 + ob];
            const float* ap = &Alds[kk * 65 + bb];
            float w0 = wp[0], w1 = wp[1], w2 = wp[2], w3 = wp[3];
#pragma unroll
            for (int j = 0; j < 4; ++j) {
                float av = ap[j];
                acc[0][j] = fmaf(w0, av, acc[0][j]);
                acc[1][j] = fmaf(w1, av, acc[1][j]);
                acc[2][j] = fmaf(w2, av, acc[2][j]);
                acc[3][j] = fmaf(w3, av, acc[3][j]);
            }
        }
    }
#pragma unroll
    for (int i = 0; i < 4; ++i)
#pragma unroll
        for (int j = 0; j < 4; ++j)
            out[(size_t)(b0 + bb + j) * 256 + n0 + ob + i] = sigmoidf_(acc[i][j] + b_out[n0 + ob + i]);
}

// ------------------------------------------------------------------
extern "C" void kernel_launch(void* const* d_in, const int* in_sizes, int n_in,
                              void* d_out, int out_size, void* d_ws, size_t ws_size,
                              hipStream_t stream) {
    const float* in_data      = (const float*)d_in[0];
    const float* memory       = (const float*)d_in[1];   // READ-ONLY
    const float* h_prev       = (const float*)d_in[2];
    const float* c_prev       = (const float*)d_in[3];
    const float* prev_reads   = (const float*)d_in[4];
    const float* prev_weights = (const float*)d_in[5];
    const float* W_ih = (const float*)d_in[6];
    const float* b_ih = (const float*)d_in[7];
    const float* W_hh = (const float*)d_in[8];
    const float* b_hh = (const float*)d_in[9];
    const float* W_out = (const float*)d_in[10];
    const float* b_out = (const float*)d_in[11];
    const float* Wk   = (const float*)d_in[12];
    const float* bk   = (const float*)d_in[13];
    const float* Wbeta = (const float*)d_in[14];
    const float* bbeta = (const float*)d_in[15];
    const float* Wg   = (const float*)d_in[16];
    const float* bg   = (const float*)d_in[17];
    const float* Ws   = (const float*)d_in[18];
    const float* bs   = (const float*)d_in[19];
    const float* Wgam = (const float*)d_in[20];
    const float* bgam = (const float*)d_in[21];
    const float* We   = (const float*)d_in[22];
    const float* be   = (const float*)d_in[23];
    const float* Wa   = (const float*)d_in[24];
    const float* ba   = (const float*)d_in[25];

    float* ws = (float*)d_ws;
    // zero region: rbuf (read accumulators) + exchange flags
    size_t o_r      = 0;                          // [4,128,64] = 32768
    size_t o_flag   = 32768;                      // 128*2*8 ints = 2048 slots
    size_t zero_floats = o_flag + 2048;           // 34816 floats (139264 B)
    // non-zeroed scratch
    size_t o_xpay   = zero_floats;                // [128*2][64] = 16384
    size_t o_gatesP = o_xpay + 16384;             // 4 x [128,2048] = 1048576
    size_t o_cheadP = o_gatesP + 1048576;         // 2 x [128,1408] = 360448
    size_t o_c      = o_cheadP + 360448;          // [128,512]
    size_t o_h      = o_c + 65536;                // [128,512]
    size_t o_keys   = o_h + 65536;                // [7,128,64] = 57344
    size_t o_knorm  = o_keys + 57344;             // [7,128] pad 1024
    size_t o_beta   = o_knorm + 1024;
    size_t o_g      = o_beta + 1024;
    size_t o_gamma  = o_g + 1024;
    size_t o_s      = o_gamma + 1024;             // [7,128,3] pad 3072
    size_t o_e      = o_s + 3072;                 // [7,128,64] = 57344
    size_t o_a      = o_e + 57344;

    float* rbuf   = ws + o_r;
    int*   xflag  = (int*)(ws + o_flag);
    float* xpay   = ws + o_xpay;
    float* gatesP = ws + o_gatesP;
    float* CheadP = ws + o_cheadP;
    float* cbuf   = ws + o_c;
    float* hbuf   = ws + o_h;
    float* keys   = ws + o_keys;
    float* knorm  = ws + o_knorm;
    float* betaA  = ws + o_beta;
    float* gA     = ws + o_g;
    float* gammaA = ws + o_gamma;
    float* sA     = ws + o_s;
    float* eA     = ws + o_e;
    float* aA     = ws + o_a;

    hipMemsetAsync(d_ws, 0, zero_floats * sizeof(float), stream);

    // controller LSTM: split-K=4 partial GEMM (no atomics) + pointwise sum
    k_gemm_gates<<<dim3(32, 2, 4), 256, 0, stream>>>(in_data, prev_reads, h_prev, W_ih, W_hh, gatesP);
    k_lstm<<<256, 256, 0, stream>>>(gatesP, b_ih, b_hh, c_prev, cbuf, hbuf);

    // head params: split-K=2 partial GEMM over the 7 live heads (head 7 dead)
    k_gemm_head<<<dim3(22, 2, 2), 256, 0, stream>>>(cbuf, Wk, Wbeta, Wg, Ws, Wgam, We, Wa, CheadP);
    k_headact<<<896, 256, 0, stream>>>(CheadP, CheadP + (size_t)BSZ * 1408,
                                       bk, bbeta, bg, bs, bgam, be, ba,
                                       keys, knorm, betaA, gA, gammaA, sA, eA, aA);

    // fused midchain: 256 persistent blocks, per-batch-pair flag sync
    k_mega<<<256, 512, 0, stream>>>(memory, prev_weights, eA, aA, keys, knorm,
                                    betaA, gA, gammaA, sA, rbuf, xpay, xflag);

    // output layer (full-K GEMM fused with bias+sigmoid)
    k_out_full<<<dim3(4, 2), 256, 0, stream>>>(hbuf, rbuf, W_out, b_out, (float*)d_out);

    (void)in_sizes; (void)n_in; (void)out_size; (void)ws_size;
}

// Round 6
// 627.020 us; speedup vs baseline: 1.0134x; 1.0134x over previous
//
#include <hip/hip_runtime.h>
#include <math.h>

#define BSZ 128
#define NN_ 4096
#define MM_ 64
#define HH_ 512
#define EPSF 1e-8f

__device__ __forceinline__ float sigmoidf_(float x) { return 1.0f / (1.0f + expf(-x)); }
__device__ __forceinline__ float softplusf_(float x) { return fmaxf(x, 0.0f) + log1pf(expf(-fabsf(x))); }

// ------------------------------------------------------------------
// gatesP[z][128,2048] = [in_data|prev_reads|h_prev][128,1024] @ [W_ih|W_hh][2048,1024]^T
// split-K=4 into separate partial buffers (NO atomics, no zero-init)
__global__ __launch_bounds__(256) void k_gemm_gates(const float* __restrict__ in_data,
                                                    const float* __restrict__ prev_reads,
                                                    const float* __restrict__ h_prev,
                                                    const float* __restrict__ W_ih,
                                                    const float* __restrict__ W_hh,
                                                    float* __restrict__ Cp) {
    __shared__ float Alds[64 * 65];
    __shared__ float Wlds[64 * 65];
    int t = threadIdx.x;
    int n0 = blockIdx.x * 64;
    int b0 = blockIdx.y * 64;
    float* C = Cp + (size_t)blockIdx.z * (BSZ * 2048);
    int ob = (t & 15) * 4;
    int bb = (t >> 4) * 4;
    float acc[4][4];
#pragma unroll
    for (int i = 0; i < 4; ++i)
#pragma unroll
        for (int j = 0; j < 4; ++j) acc[i][j] = 0.f;
    for (int kt = 0; kt < 4; ++kt) {
        int k0 = blockIdx.z * 256 + kt * 64;
        __syncthreads();
        for (int i = 0; i < 4; ++i) {
            int f = t + 256 * i;
            int row = f >> 4, kk = (f & 15) * 4;
            int k = k0 + kk;
            float4 v;
            if (k < 256) v = *(const float4*)(in_data + ((b0 + row) << 8) + k);
            else if (k < 512) {
                int q = k - 256;
                v = *(const float4*)(prev_reads + (((q >> 6) * BSZ + b0 + row) << 6) + (q & 63));
            } else v = *(const float4*)(h_prev + ((b0 + row) << 9) + (k - 512));
            Alds[(kk + 0) * 65 + row] = v.x;
            Alds[(kk + 1) * 65 + row] = v.y;
            Alds[(kk + 2) * 65 + row] = v.z;
            Alds[(kk + 3) * 65 + row] = v.w;
        }
        for (int i = 0; i < 4; ++i) {
            int f = t + 256 * i;
            int o = f >> 4, kk = (f & 15) * 4;
            int j = n0 + o, k = k0 + kk;
            const float* src = (k < 512) ? (W_ih + (size_t)j * 512 + k)
                                         : (W_hh + (size_t)j * 512 + (k - 512));
            float4 v = *(const float4*)src;
            Wlds[(kk + 0) * 65 + o] = v.x;
            Wlds[(kk + 1) * 65 + o] = v.y;
            Wlds[(kk + 2) * 65 + o] = v.z;
            Wlds[(kk + 3) * 65 + o] = v.w;
        }
        __syncthreads();
        for (int kk = 0; kk < 64; ++kk) {
            const float* wp = &Wlds[kk * 65 + ob];
            const float* ap = &Alds[kk * 65 + bb];
            float w0 = wp[0], w1 = wp[1], w2 = wp[2], w3 = wp[3];
#pragma unroll
            for (int j = 0; j < 4; ++j) {
                float av = ap[j];
                acc[0][j] = fmaf(w0, av, acc[0][j]);
                acc[1][j] = fmaf(w1, av, acc[1][j]);
                acc[2][j] = fmaf(w2, av, acc[2][j]);
                acc[3][j] = fmaf(w3, av, acc[3][j]);
            }
        }
    }
#pragma unroll
    for (int i = 0; i < 4; ++i)
#pragma unroll
        for (int j = 0; j < 4; ++j)
            C[(size_t)(b0 + bb + j) * 2048 + n0 + ob + i] = acc[i][j];
}

// ------------------------------------------------------------------
// LSTM pointwise, summing the 4 gate partials
__global__ void k_lstm(const float* __restrict__ gatesP, const float* __restrict__ b_ih,
                       const float* __restrict__ b_hh, const float* __restrict__ c_prev,
                       float* __restrict__ cbuf, float* __restrict__ hbuf) {
    int idx = blockIdx.x * blockDim.x + threadIdx.x;
    if (idx >= BSZ * HH_) return;
    int b = idx >> 9, j = idx & 511;
    float gi = b_ih[j]        + b_hh[j];
    float gf = b_ih[512 + j]  + b_hh[512 + j];
    float gg = b_ih[1024 + j] + b_hh[1024 + j];
    float go = b_ih[1536 + j] + b_hh[1536 + j];
#pragma unroll
    for (int p = 0; p < 4; ++p) {
        const float* gr = gatesP + (size_t)p * (BSZ * 2048) + (size_t)b * 2048;
        gi += gr[j];
        gf += gr[512 + j];
        gg += gr[1024 + j];
        go += gr[1536 + j];
    }
    float cc = sigmoidf_(gf) * c_prev[idx] + sigmoidf_(gi) * tanhf(gg);
    float hh = sigmoidf_(go) * tanhf(cc);
    cbuf[idx] = cc;
    hbuf[idx] = hh;
}

// ------------------------------------------------------------------
__device__ __forceinline__ const float* whead_row_ptr(const float* Wk, const float* Wbeta,
                                                      const float* Wg, const float* Ws,
                                                      const float* Wgam, const float* We,
                                                      const float* Wa, int r) {
    int i = r / 198, q = r - i * 198;
    if (q < 64)  return Wk + (size_t)((i << 6) + q) * 512;
    if (q == 64) return Wbeta + (size_t)i * 512;
    if (q == 65) return Wg + (size_t)i * 512;
    if (q <= 68) return Ws + (size_t)(i * 3 + q - 66) * 512;
    if (q == 69) return Wgam + (size_t)i * 512;
    if (q < 134) return We + (size_t)((i << 6) + q - 70) * 512;
    return Wa + (size_t)((i << 6) + q - 134) * 512;
}

__global__ __launch_bounds__(256) void k_gemm_head(const float* __restrict__ A,
                                                   const float* __restrict__ Wk,
                                                   const float* __restrict__ Wbeta,
                                                   const float* __restrict__ Wg,
                                                   const float* __restrict__ Ws,
                                                   const float* __restrict__ Wgam,
                                                   const float* __restrict__ We,
                                                   const float* __restrict__ Wa,
                                                   float* __restrict__ Cp) {
    __shared__ float Alds[64 * 65];
    __shared__ float Wlds[64 * 65];
    int t = threadIdx.x;
    int n0 = blockIdx.x * 64;
    int b0 = blockIdx.y * 64;
    float* C = Cp + (size_t)blockIdx.z * (BSZ * 1408);
    int ob = (t & 15) * 4;
    int bb = (t >> 4) * 4;
    float acc[4][4];
#pragma unroll
    for (int i = 0; i < 4; ++i)
#pragma unroll
        for (int j = 0; j < 4; ++j) acc[i][j] = 0.f;
    for (int kt = 0; kt < 4; ++kt) {
        int k0 = blockIdx.z * 256 + kt * 64;
        __syncthreads();
        for (int i = 0; i < 4; ++i) {
            int f = t + 256 * i;
            int row = f >> 4, kk = (f & 15) * 4;
            float4 v = *(const float4*)(A + (size_t)(b0 + row) * 512 + k0 + kk);
            Alds[(kk + 0) * 65 + row] = v.x;
            Alds[(kk + 1) * 65 + row] = v.y;
            Alds[(kk + 2) * 65 + row] = v.z;
            Alds[(kk + 3) * 65 + row] = v.w;
        }
        for (int i = 0; i < 4; ++i) {
            int f = t + 256 * i;
            int o = f >> 4, kk = (f & 15) * 4;
            int r = n0 + o;
            float4 v = make_float4(0.f, 0.f, 0.f, 0.f);
            if (r < 1386) {
                const float* p = whead_row_ptr(Wk, Wbeta, Wg, Ws, Wgam, We, Wa, r) + k0 + kk;
                v = *(const float4*)p;
            }
            Wlds[(kk + 0) * 65 + o] = v.x;
            Wlds[(kk + 1) * 65 + o] = v.y;
            Wlds[(kk + 2) * 65 + o] = v.z;
            Wlds[(kk + 3) * 65 + o] = v.w;
        }
        __syncthreads();
        for (int kk = 0; kk < 64; ++kk) {
            const float* wp = &Wlds[kk * 65 + ob];
            const float* ap = &Alds[kk * 65 + bb];
            float w0 = wp[0], w1 = wp[1], w2 = wp[2], w3 = wp[3];
#pragma unroll
            for (int j = 0; j < 4; ++j) {
                float av = ap[j];
                acc[0][j] = fmaf(w0, av, acc[0][j]);
                acc[1][j] = fmaf(w1, av, acc[1][j]);
                acc[2][j] = fmaf(w2, av, acc[2][j]);
                acc[3][j] = fmaf(w3, av, acc[3][j]);
            }
        }
    }
#pragma unroll
    for (int i = 0; i < 4; ++i)
#pragma unroll
        for (int j = 0; j < 4; ++j)
            C[(size_t)(b0 + bb + j) * 1408 + n0 + ob + i] = acc[i][j];
}

// ------------------------------------------------------------------
// per (head<7, b): sum 2 partials + bias + activations
__global__ __launch_bounds__(256) void k_headact(const float* __restrict__ C0,
                                                 const float* __restrict__ C1,
                                                 const float* __restrict__ bk, const float* __restrict__ bbeta,
                                                 const float* __restrict__ bg, const float* __restrict__ bs,
                                                 const float* __restrict__ bgam, const float* __restrict__ be,
                                                 const float* __restrict__ ba,
                                                 float* __restrict__ keys, float* __restrict__ knorm,
                                                 float* __restrict__ betaA, float* __restrict__ gA,
                                                 float* __restrict__ gammaA, float* __restrict__ sA,
                                                 float* __restrict__ eA, float* __restrict__ aA) {
    __shared__ float sk[64];
    __shared__ float s3[3];
    int blk = blockIdx.x;
    int i = blk >> 7, b = blk & 127;
    int q = threadIdx.x;
    float val = 0.f;
    if (q < 198) {
        float bv = (q < 64)   ? bk[(i << 6) + q]
                 : (q == 64)  ? bbeta[i]
                 : (q == 65)  ? bg[i]
                 : (q <= 68)  ? bs[i * 3 + q - 66]
                 : (q == 69)  ? bgam[i]
                 : (q < 134)  ? be[(i << 6) + q - 70]
                              : ba[(i << 6) + q - 134];
        size_t idx = (size_t)b * 1408 + i * 198 + q;
        val = C0[idx] + C1[idx] + bv;
    }
    if (q < 64) { keys[(size_t)(i * BSZ + b) * 64 + q] = val; sk[q] = val * val; }
    if (q >= 66 && q <= 68) s3[q - 66] = val;
    __syncthreads();
    if (q == 0) {
        float s = 0.f;
        for (int m2 = 0; m2 < 64; ++m2) s += sk[m2];
        knorm[i * BSZ + b] = sqrtf(s);
    }
    if (q == 64) betaA[i * BSZ + b] = softplusf_(val);
    if (q == 65) gA[i * BSZ + b] = sigmoidf_(val);
    if (q == 69) gammaA[i * BSZ + b] = 1.f + softplusf_(val);
    if (q == 66) {
        float mx = fmaxf(s3[0], fmaxf(s3[1], s3[2]));
        float e0 = expf(s3[0] - mx), e1 = expf(s3[1] - mx), e2 = expf(s3[2] - mx);
        float inv = 1.f / (e0 + e1 + e2);
        sA[(i * BSZ + b) * 3 + 0] = e0 * inv;
        sA[(i * BSZ + b) * 3 + 1] = e1 * inv;
        sA[(i * BSZ + b) * 3 + 2] = e2 * inv;
    }
    if (q >= 70 && q < 134)  eA[(size_t)(i * BSZ + b) * 64 + (q - 70)] = sigmoidf_(val);
    if (q >= 134 && q < 198) aA[(size_t)(i * BSZ + b) * 64 + (q - 134)] = tanhf(val);
}

// ------------------------------------------------------------------
// READ-ONLY sweep over pristine mem0. Reconstructs updated memory states in
// registers from write weights w1/w3/w5 + per-batch e/a vectors. Computes up
// to 2 sims on state `napply` — storing exp(beta*sim) (max-free softmax,
// |beta*sim| <~ 3) and atomically accumulating the per-(head,b) exp-sum —
// and a read-accumulate on state `read_state`.
// grid = B*N/64 blocks of 256; 16 lanes per row (float4 per lane)
__global__ __launch_bounds__(256) void k_pass2(const float* __restrict__ mem,
                                               const float* __restrict__ wbuf,
                                               const float* __restrict__ eA, const float* __restrict__ aA,
                                               const float* __restrict__ keys, const float* __restrict__ knorm,
                                               const float* __restrict__ betaA,
                                               float* __restrict__ sxp, float* __restrict__ expsum,
                                               float* __restrict__ r_out,
                                               int napply, int nsims, int sh0, int sh1,
                                               int read_state, int read_head, int read_idx) {
    __shared__ __align__(16) float rbuf[16][64];
    __shared__ float esmem[16][2];
    int t = threadIdx.x;
    int lane = t & 15, grp = t >> 4;
    int base = blockIdx.x * 64;       // 64 consecutive rows, same b
    int b = base >> 12;
    int m4 = lane * 4;
    float4 e1 = *(const float4*)(eA + (size_t)(1 * BSZ + b) * 64 + m4);
    float4 a1 = *(const float4*)(aA + (size_t)(1 * BSZ + b) * 64 + m4);
    float4 e3 = *(const float4*)(eA + (size_t)(3 * BSZ + b) * 64 + m4);
    float4 a3 = *(const float4*)(aA + (size_t)(3 * BSZ + b) * 64 + m4);
    float4 e5 = *(const float4*)(eA + (size_t)(5 * BSZ + b) * 64 + m4);
    float4 a5 = *(const float4*)(aA + (size_t)(5 * BSZ + b) * 64 + m4);
    float4 k0v = make_float4(0.f, 0.f, 0.f, 0.f), k1v = k0v;
    float kn0v = 0.f, kn1v = 0.f, bet0 = 0.f, bet1 = 0.f;
    if (nsims > 0) {
        k0v = *(const float4*)(keys + (size_t)(sh0 * BSZ + b) * 64 + m4);
        kn0v = knorm[sh0 * BSZ + b];
        bet0 = betaA[sh0 * BSZ + b];
    }
    if (nsims > 1) {
        k1v = *(const float4*)(keys + (size_t)(sh1 * BSZ + b) * 64 + m4);
        kn1v = knorm[sh1 * BSZ + b];
        bet1 = betaA[sh1 * BSZ + b];
    }
    const float* w1p = wbuf + (size_t)1 * BSZ * NN_;
    const float* w3p = wbuf + (size_t)3 * BSZ * NN_;
    const float* w5p = wbuf + (size_t)5 * BSZ * NN_;
    const float* wrp = (read_head >= 0) ? (wbuf + (size_t)read_head * BSZ * NN_) : nullptr;
    float* sim0 = sxp + (size_t)sh0 * BSZ * NN_;
    float* sim1 = sxp + (size_t)sh1 * BSZ * NN_;

    float4 racc = make_float4(0.f, 0.f, 0.f, 0.f);
    float esum0 = 0.f, esum1 = 0.f;
    for (int it = 0; it < 4; ++it) {
        int row = base + it * 16 + grp;
        float4 m = *(const float4*)(mem + (size_t)row * 64 + m4);
        float4 mr = m;
        if (napply >= 1) {
            float w = w1p[row];
            m.x = m.x * (1.f - w * e1.x) + w * a1.x;
            m.y = m.y * (1.f - w * e1.y) + w * a1.y;
            m.z = m.z * (1.f - w * e1.z) + w * a1.z;
            m.w = m.w * (1.f - w * e1.w) + w * a1.w;
            if (read_state == 1) mr = m;
        }
        if (napply >= 2) {
            float w = w3p[row];
            m.x = m.x * (1.f - w * e3.x) + w * a3.x;
            m.y = m.y * (1.f - w * e3.y) + w * a3.y;
            m.z = m.z * (1.f - w * e3.z) + w * a3.z;
            m.w = m.w * (1.f - w * e3.w) + w * a3.w;
            if (read_state == 2) mr = m;
        }
        if (napply >= 3) {
            float w = w5p[row];
            m.x = m.x * (1.f - w * e5.x) + w * a5.x;
            m.y = m.y * (1.f - w * e5.y) + w * a5.y;
            m.z = m.z * (1.f - w * e5.z) + w * a5.z;
            m.w = m.w * (1.f - w * e5.w) + w * a5.w;
            if (read_state == 3) mr = m;
        }
        if (read_head >= 0) {
            float wr = wrp[row];
            racc.x = fmaf(wr, mr.x, racc.x);
            racc.y = fmaf(wr, mr.y, racc.y);
            racc.z = fmaf(wr, mr.z, racc.z);
            racc.w = fmaf(wr, mr.w, racc.w);
        }
        if (nsims > 0) {
            float d0 = m.x * k0v.x + m.y * k0v.y + m.z * k0v.z + m.w * k0v.w;
            float nn = m.x * m.x + m.y * m.y + m.z * m.z + m.w * m.w;
            float d1 = 0.f;
            if (nsims > 1) d1 = m.x * k1v.x + m.y * k1v.y + m.z * k1v.z + m.w * k1v.w;
#pragma unroll
            for (int off = 8; off >= 1; off >>= 1) {
                d0 += __shfl_xor(d0, off, 16);
                nn += __shfl_xor(nn, off, 16);
                if (nsims > 1) d1 += __shfl_xor(d1, off, 16);
            }
            if (lane == 0) {
                float nm = sqrtf(nn);
                float v0 = expf(bet0 * (d0 / (nm * kn0v + EPSF)));
                sim0[row] = v0;
                esum0 += v0;
                if (nsims > 1) {
                    float v1 = expf(bet1 * (d1 / (nm * kn1v + EPSF)));
                    sim1[row] = v1;
                    esum1 += v1;
                }
            }
        }
    }
    if (nsims > 0) {
        if (lane == 0) { esmem[grp][0] = esum0; esmem[grp][1] = esum1; }
        __syncthreads();
        if (t == 0) {
            float tot0 = 0.f, tot1 = 0.f;
#pragma unroll
            for (int g2 = 0; g2 < 16; ++g2) { tot0 += esmem[g2][0]; tot1 += esmem[g2][1]; }
            atomicAdd(&expsum[sh0 * BSZ + b], tot0);
            if (nsims > 1) atomicAdd(&expsum[sh1 * BSZ + b], tot1);
        }
    }
    if (read_head >= 0) {
        *(float4*)(&rbuf[grp][m4]) = racc;
        __syncthreads();
        if (t < 64) {
            float s = 0.f;
#pragma unroll
            for (int g2 = 0; g2 < 16; ++g2) s += rbuf[g2][t];
            atomicAdd(&r_out[(size_t)(read_idx * BSZ + b) * 64 + t], s);
        }
    }
}

// ------------------------------------------------------------------
// per (head, b): interpolate (exp values + precomputed exp-sum) -> shift ->
// sharpen -> normalize.  1024 threads; 1 LDS pass + 1 reduction (2 barriers).
__global__ __launch_bounds__(1024) void k_weights(const float* __restrict__ sxp,
                                                  const float* __restrict__ prev_w,
                                                  const float* __restrict__ expsum,
                                                  const float* __restrict__ gA,
                                                  const float* __restrict__ gammaA, const float* __restrict__ sA,
                                                  float* __restrict__ wout_base, int head0) {
    __shared__ float wg[NN_];
    __shared__ float redp[16];
    int h = head0 + blockIdx.y, b = blockIdx.x;
    int hb = h * BSZ + b;
    float g = gA[hb], gamma = gammaA[hb];
    float s0 = sA[hb * 3 + 0], s1 = sA[hb * 3 + 1], s2 = sA[hb * 3 + 2];
    float ginvS = g / expsum[hb];
    const float* sp = sxp + (size_t)hb * NN_;
    const float* pw = prev_w + (size_t)hb * NN_;
    float* wout = wout_base + (size_t)hb * NN_;
    int t = threadIdx.x, wv = t >> 6, ln = t & 63;
#pragma unroll
    for (int j = 0; j < 4; ++j) {
        int n = t + 1024 * j;
        wg[n] = ginvS * sp[n] + (1.f - g) * pw[n];
    }
    __syncthreads();
    float tv[4];
    float lsum2 = 0.f;
#pragma unroll
    for (int j = 0; j < 4; ++j) {
        int n = t + 1024 * j;
        float wsft = s0 * wg[(n + 1) & (NN_ - 1)] + s1 * wg[n] + s2 * wg[(n - 1) & (NN_ - 1)];
        float wp = powf(wsft, gamma);
        tv[j] = wp;
        lsum2 += wp;
    }
#pragma unroll
    for (int off = 32; off >= 1; off >>= 1) lsum2 += __shfl_xor(lsum2, off);
    if (ln == 0) redp[wv] = lsum2;
    __syncthreads();
    float S2 = 0.f;
#pragma unroll
    for (int k = 0; k < 16; ++k) S2 += redp[k];
    float inv2 = 1.f / (S2 + EPSF);
#pragma unroll
    for (int j = 0; j < 4; ++j) wout[t + 1024 * j] = tv[j] * inv2;
}

// ------------------------------------------------------------------
// out[128,256] = sigmoid([hbuf|rbuf][128,768] @ W_out[256,768]^T + b_out)
__global__ __launch_bounds__(256) void k_out_full(const float* __restrict__ hbuf,
                                                  const float* __restrict__ rbuf,
                                                  const float* __restrict__ W_out,
                                                  const float* __restrict__ b_out,
                                                  float* __restrict__ out) {
    __shared__ float Alds[64 * 65];
    __shared__ float Wlds[64 * 65];
    int t = threadIdx.x;
    int n0 = blockIdx.x * 64;
    int b0 = blockIdx.y * 64;
    int ob = (t & 15) * 4;
    int bb = (t >> 4) * 4;
    float acc[4][4];
#pragma unroll
    for (int i = 0; i < 4; ++i)
#pragma unroll
        for (int j = 0; j < 4; ++j) acc[i][j] = 0.f;
    for (int k0 = 0; k0 < 768; k0 += 64) {
        __syncthreads();
        for (int i = 0; i < 4; ++i) {
            int f = t + 256 * i;
            int rb = f >> 4, kk = (f & 15) * 4;
            int k = k0 + kk;
            float4 v;
            if (k < 512) v = *(const float4*)(hbuf + ((b0 + rb) << 9) + k);
            else {
                int q = k - 512;
                v = *(const float4*)(rbuf + (((q >> 6) * BSZ + b0 + rb) << 6) + (q & 63));
            }
            Alds[(kk + 0) * 65 + rb] = v.x;
            Alds[(kk + 1) * 65 + rb] = v.y;
            Alds[(kk + 2) * 65 + rb] = v.z;
            Alds[(kk + 3) * 65 + rb] = v.w;
        }
        for (int i = 0; i < 4; ++i) {
            int f = t + 256 * i;
            int o = f >> 4, kk = (f & 15) * 4;
            float4 v = *(const float4*)(W_out + (size_t)(n0 + o) * 768 + k0 + kk);
            Wlds[(kk + 0) * 65 + o] = v.x;
            Wlds[(kk + 1) * 65 + o] = v.y;
            Wlds[(kk + 2) * 65 + o] = v.z;
            Wlds[(kk + 3) * 65 + o] = v.w;
        }
        __syncthreads();
        for (int kk = 0; kk < 64; ++kk) {
            const float* wp = &Wlds[kk * 65 + ob];
            const float* ap = &Alds[kk * 65 + bb];
            float w0 = wp[0], w1 = wp[1], w2 = wp[2], w3 = wp[3];
#pragma unroll
            for (int j = 0; j < 4; ++j) {
                float av = ap[j];
                acc[0][j] = fmaf(w0, av, acc[0][j]);
                acc[1][j] = fmaf(w1, av, acc[1][j]);
                acc[2][j] = fmaf(w2, av, acc[2][j]);
                acc[3][j] = fmaf(w3, av, acc[3][j]);
            }
        }
    }
#pragma unroll
    for (int i = 0; i < 4; ++i)
#pragma unroll
        for (int j = 0; j < 4; ++j)
            out[(size_t)(b0 + bb + j) * 256 + n0 + ob + i] = sigmoidf_(acc[i][j] + b_out[n0 + ob + i]);
}

// ------------------------------------------------------------------
extern "C" void kernel_launch(void* const* d_in, const int* in_sizes, int n_in,
                              void* d_out, int out_size, void* d_ws, size_t ws_size,
                              hipStream_t stream) {
    const float* in_data      = (const float*)d_in[0];
    const float* memory       = (const float*)d_in[1];   // READ-ONLY
    const float* h_prev       = (const float*)d_in[2];
    const float* c_prev       = (const float*)d_in[3];
    const float* prev_reads   = (const float*)d_in[4];
    const float* prev_weights = (const float*)d_in[5];
    const float* W_ih = (const float*)d_in[6];
    const float* b_ih = (const float*)d_in[7];
    const float* W_hh = (const float*)d_in[8];
    const float* b_hh = (const float*)d_in[9];
    const float* W_out = (const float*)d_in[10];
    const float* b_out = (const float*)d_in[11];
    const float* Wk   = (const float*)d_in[12];
    const float* bk   = (const float*)d_in[13];
    const float* Wbeta = (const float*)d_in[14];
    const float* bbeta = (const float*)d_in[15];
    const float* Wg   = (const float*)d_in[16];
    const float* bg   = (const float*)d_in[17];
    const float* Ws   = (const float*)d_in[18];
    const float* bs   = (const float*)d_in[19];
    const float* Wgam = (const float*)d_in[20];
    const float* bgam = (const float*)d_in[21];
    const float* We   = (const float*)d_in[22];
    const float* be   = (const float*)d_in[23];
    const float* Wa   = (const float*)d_in[24];
    const float* ba   = (const float*)d_in[25];

    float* ws = (float*)d_ws;
    // zero region: rbuf (read accumulators) + per-(head,b) exp-sums
    size_t o_r      = 0;                          // [4,128,64] = 32768
    size_t o_esum   = 32768;                      // [7,128] pad 1024
    size_t zero_floats = o_esum + 1024;           // 33792 floats (135 KB)
    // non-zeroed scratch
    size_t o_gatesP = zero_floats;                // 4 x [128,2048] = 1048576
    size_t o_cheadP = o_gatesP + 1048576;         // 2 x [128,1408] = 360448
    size_t o_c      = o_cheadP + 360448;          // [128,512]
    size_t o_h      = o_c + 65536;                // [128,512]
    size_t o_keys   = o_h + 65536;                // [7,128,64] = 57344
    size_t o_knorm  = o_keys + 57344;             // [7,128] pad 1024
    size_t o_beta   = o_knorm + 1024;
    size_t o_g      = o_beta + 1024;
    size_t o_gamma  = o_g + 1024;
    size_t o_s      = o_gamma + 1024;             // [7,128,3] pad 3072
    size_t o_e      = o_s + 3072;                 // [7,128,64] = 57344
    size_t o_a      = o_e + 57344;
    size_t o_sxp    = o_a + 57344;                // [7,128,4096] = 3670016
    size_t o_w      = o_sxp + 3670016;            // [7,128,4096] = 3670016

    float* rbuf   = ws + o_r;
    float* esum   = ws + o_esum;
    float* gatesP = ws + o_gatesP;
    float* CheadP = ws + o_cheadP;
    float* cbuf   = ws + o_c;
    float* hbuf   = ws + o_h;
    float* keys   = ws + o_keys;
    float* knorm  = ws + o_knorm;
    float* betaA  = ws + o_beta;
    float* gA     = ws + o_g;
    float* gammaA = ws + o_gamma;
    float* sA     = ws + o_s;
    float* eA     = ws + o_e;
    float* aA     = ws + o_a;
    float* sxp    = ws + o_sxp;
    float* wbuf   = ws + o_w;

    hipMemsetAsync(d_ws, 0, zero_floats * sizeof(float), stream);

    // controller LSTM: split-K=4 partial GEMM (no atomics) + pointwise sum
    k_gemm_gates<<<dim3(32, 2, 4), 256, 0, stream>>>(in_data, prev_reads, h_prev, W_ih, W_hh, gatesP);
    k_lstm<<<256, 256, 0, stream>>>(gatesP, b_ih, b_hh, c_prev, cbuf, hbuf);

    // head params: split-K=2 partial GEMM over the 7 live heads (head 7 dead)
    k_gemm_head<<<dim3(22, 2, 2), 256, 0, stream>>>(cbuf, Wk, Wbeta, Wg, Ws, Wgam, We, Wa, CheadP);
    k_headact<<<896, 256, 0, stream>>>(CheadP, CheadP + (size_t)BSZ * 1408,
                                       bk, bbeta, bg, bs, bgam, be, ba,
                                       keys, knorm, betaA, gA, gammaA, sA, eA, aA);

    const int PB = BSZ * NN_ / 64;  // 8192 blocks per sweep
    // S0: sims heads 0,1 on mem0 (exp + expsum folded in)
    k_pass2<<<PB, 256, 0, stream>>>(memory, wbuf, eA, aA, keys, knorm, betaA, sxp, esum, rbuf,
                                    0, 2, 0, 1, -1, -1, 0);
    k_weights<<<dim3(128, 2), 1024, 0, stream>>>(sxp, prev_weights, esum, gA, gammaA, sA, wbuf, 0);
    // S1: sims heads 2,3 on mem1 (apply w1); r0 from mem0
    k_pass2<<<PB, 256, 0, stream>>>(memory, wbuf, eA, aA, keys, knorm, betaA, sxp, esum, rbuf,
                                    1, 2, 2, 3, 0, 0, 0);
    k_weights<<<dim3(128, 2), 1024, 0, stream>>>(sxp, prev_weights, esum, gA, gammaA, sA, wbuf, 2);
    // S2: sims heads 4,5 on mem2 (apply w1,w3); r2 from mem1
    k_pass2<<<PB, 256, 0, stream>>>(memory, wbuf, eA, aA, keys, knorm, betaA, sxp, esum, rbuf,
                                    2, 2, 4, 5, 1, 2, 1);
    k_weights<<<dim3(128, 2), 1024, 0, stream>>>(sxp, prev_weights, esum, gA, gammaA, sA, wbuf, 4);
    // S3: sim head 6 on mem3 (apply w1,w3,w5); r4 from mem2
    k_pass2<<<PB, 256, 0, stream>>>(memory, wbuf, eA, aA, keys, knorm, betaA, sxp, esum, rbuf,
                                    3, 1, 6, 6, 2, 4, 2);
    k_weights<<<dim3(128, 1), 1024, 0, stream>>>(sxp, prev_weights, esum, gA, gammaA, sA, wbuf, 6);
    // S4: r6 from mem3; head 7 dead
    k_pass2<<<PB, 256, 0, stream>>>(memory, wbuf, eA, aA, keys, knorm, betaA, sxp, esum, rbuf,
                                    3, 0, 0, 0, 3, 6, 3);

    // output layer (full-K GEMM fused with bias+sigmoid)
    k_out_full<<<dim3(4, 2), 256, 0, stream>>>(hbuf, rbuf, W_out, b_out, (float*)d_out);

    (void)in_sizes; (void)n_in; (void)out_size; (void)ws_size;
}

// Round 7
// 532.062 us; speedup vs baseline: 1.1943x; 1.1785x over previous
//
#include <hip/hip_runtime.h>
#include <math.h>

#define BSZ 128
#define NN_ 4096
#define MM_ 64
#define HH_ 512
#define EPSF 1e-8f

__device__ __forceinline__ float sigmoidf_(float x) { return 1.0f / (1.0f + expf(-x)); }
__device__ __forceinline__ float softplusf_(float x) { return fmaxf(x, 0.0f) + log1pf(expf(-fabsf(x))); }

// ------------------------------------------------------------------
// gatesP[z][128,2048] = [in_data|prev_reads|h_prev][128,1024] @ [W_ih|W_hh][2048,1024]^T
// split-K=4 into separate partial buffers (NO atomics, no zero-init)
__global__ __launch_bounds__(256) void k_gemm_gates(const float* __restrict__ in_data,
                                                    const float* __restrict__ prev_reads,
                                                    const float* __restrict__ h_prev,
                                                    const float* __restrict__ W_ih,
                                                    const float* __restrict__ W_hh,
                                                    float* __restrict__ Cp) {
    __shared__ float Alds[64 * 65];
    __shared__ float Wlds[64 * 65];
    int t = threadIdx.x;
    int n0 = blockIdx.x * 64;
    int b0 = blockIdx.y * 64;
    float* C = Cp + (size_t)blockIdx.z * (BSZ * 2048);
    int ob = (t & 15) * 4;
    int bb = (t >> 4) * 4;
    float acc[4][4];
#pragma unroll
    for (int i = 0; i < 4; ++i)
#pragma unroll
        for (int j = 0; j < 4; ++j) acc[i][j] = 0.f;
    for (int kt = 0; kt < 4; ++kt) {
        int k0 = blockIdx.z * 256 + kt * 64;
        __syncthreads();
        for (int i = 0; i < 4; ++i) {
            int f = t + 256 * i;
            int row = f >> 4, kk = (f & 15) * 4;
            int k = k0 + kk;
            float4 v;
            if (k < 256) v = *(const float4*)(in_data + ((b0 + row) << 8) + k);
            else if (k < 512) {
                int q = k - 256;
                v = *(const float4*)(prev_reads + (((q >> 6) * BSZ + b0 + row) << 6) + (q & 63));
            } else v = *(const float4*)(h_prev + ((b0 + row) << 9) + (k - 512));
            Alds[(kk + 0) * 65 + row] = v.x;
            Alds[(kk + 1) * 65 + row] = v.y;
            Alds[(kk + 2) * 65 + row] = v.z;
            Alds[(kk + 3) * 65 + row] = v.w;
        }
        for (int i = 0; i < 4; ++i) {
            int f = t + 256 * i;
            int o = f >> 4, kk = (f & 15) * 4;
            int j = n0 + o, k = k0 + kk;
            const float* src = (k < 512) ? (W_ih + (size_t)j * 512 + k)
                                         : (W_hh + (size_t)j * 512 + (k - 512));
            float4 v = *(const float4*)src;
            Wlds[(kk + 0) * 65 + o] = v.x;
            Wlds[(kk + 1) * 65 + o] = v.y;
            Wlds[(kk + 2) * 65 + o] = v.z;
            Wlds[(kk + 3) * 65 + o] = v.w;
        }
        __syncthreads();
        for (int kk = 0; kk < 64; ++kk) {
            const float* wp = &Wlds[kk * 65 + ob];
            const float* ap = &Alds[kk * 65 + bb];
            float w0 = wp[0], w1 = wp[1], w2 = wp[2], w3 = wp[3];
#pragma unroll
            for (int j = 0; j < 4; ++j) {
                float av = ap[j];
                acc[0][j] = fmaf(w0, av, acc[0][j]);
                acc[1][j] = fmaf(w1, av, acc[1][j]);
                acc[2][j] = fmaf(w2, av, acc[2][j]);
                acc[3][j] = fmaf(w3, av, acc[3][j]);
            }
        }
    }
#pragma unroll
    for (int i = 0; i < 4; ++i)
#pragma unroll
        for (int j = 0; j < 4; ++j)
            C[(size_t)(b0 + bb + j) * 2048 + n0 + ob + i] = acc[i][j];
}

// ------------------------------------------------------------------
// LSTM pointwise, summing the 4 gate partials
__global__ void k_lstm(const float* __restrict__ gatesP, const float* __restrict__ b_ih,
                       const float* __restrict__ b_hh, const float* __restrict__ c_prev,
                       float* __restrict__ cbuf, float* __restrict__ hbuf) {
    int idx = blockIdx.x * blockDim.x + threadIdx.x;
    if (idx >= BSZ * HH_) return;
    int b = idx >> 9, j = idx & 511;
    float gi = b_ih[j]        + b_hh[j];
    float gf = b_ih[512 + j]  + b_hh[512 + j];
    float gg = b_ih[1024 + j] + b_hh[1024 + j];
    float go = b_ih[1536 + j] + b_hh[1536 + j];
#pragma unroll
    for (int p = 0; p < 4; ++p) {
        const float* gr = gatesP + (size_t)p * (BSZ * 2048) + (size_t)b * 2048;
        gi += gr[j];
        gf += gr[512 + j];
        gg += gr[1024 + j];
        go += gr[1536 + j];
    }
    float cc = sigmoidf_(gf) * c_prev[idx] + sigmoidf_(gi) * tanhf(gg);
    float hh = sigmoidf_(go) * tanhf(cc);
    cbuf[idx] = cc;
    hbuf[idx] = hh;
}

// ------------------------------------------------------------------
__device__ __forceinline__ const float* whead_row_ptr(const float* Wk, const float* Wbeta,
                                                      const float* Wg, const float* Ws,
                                                      const float* Wgam, const float* We,
                                                      const float* Wa, int r) {
    int i = r / 198, q = r - i * 198;
    if (q < 64)  return Wk + (size_t)((i << 6) + q) * 512;
    if (q == 64) return Wbeta + (size_t)i * 512;
    if (q == 65) return Wg + (size_t)i * 512;
    if (q <= 68) return Ws + (size_t)(i * 3 + q - 66) * 512;
    if (q == 69) return Wgam + (size_t)i * 512;
    if (q < 134) return We + (size_t)((i << 6) + q - 70) * 512;
    return Wa + (size_t)((i << 6) + q - 134) * 512;
}

__global__ __launch_bounds__(256) void k_gemm_head(const float* __restrict__ A,
                                                   const float* __restrict__ Wk,
                                                   const float* __restrict__ Wbeta,
                                                   const float* __restrict__ Wg,
                                                   const float* __restrict__ Ws,
                                                   const float* __restrict__ Wgam,
                                                   const float* __restrict__ We,
                                                   const float* __restrict__ Wa,
                                                   float* __restrict__ Cp) {
    __shared__ float Alds[64 * 65];
    __shared__ float Wlds[64 * 65];
    int t = threadIdx.x;
    int n0 = blockIdx.x * 64;
    int b0 = blockIdx.y * 64;
    float* C = Cp + (size_t)blockIdx.z * (BSZ * 1408);
    int ob = (t & 15) * 4;
    int bb = (t >> 4) * 4;
    float acc[4][4];
#pragma unroll
    for (int i = 0; i < 4; ++i)
#pragma unroll
        for (int j = 0; j < 4; ++j) acc[i][j] = 0.f;
    for (int kt = 0; kt < 4; ++kt) {
        int k0 = blockIdx.z * 256 + kt * 64;
        __syncthreads();
        for (int i = 0; i < 4; ++i) {
            int f = t + 256 * i;
            int row = f >> 4, kk = (f & 15) * 4;
            float4 v = *(const float4*)(A + (size_t)(b0 + row) * 512 + k0 + kk);
            Alds[(kk + 0) * 65 + row] = v.x;
            Alds[(kk + 1) * 65 + row] = v.y;
            Alds[(kk + 2) * 65 + row] = v.z;
            Alds[(kk + 3) * 65 + row] = v.w;
        }
        for (int i = 0; i < 4; ++i) {
            int f = t + 256 * i;
            int o = f >> 4, kk = (f & 15) * 4;
            int r = n0 + o;
            float4 v = make_float4(0.f, 0.f, 0.f, 0.f);
            if (r < 1386) {
                const float* p = whead_row_ptr(Wk, Wbeta, Wg, Ws, Wgam, We, Wa, r) + k0 + kk;
                v = *(const float4*)p;
            }
            Wlds[(kk + 0) * 65 + o] = v.x;
            Wlds[(kk + 1) * 65 + o] = v.y;
            Wlds[(kk + 2) * 65 + o] = v.z;
            Wlds[(kk + 3) * 65 + o] = v.w;
        }
        __syncthreads();
        for (int kk = 0; kk < 64; ++kk) {
            const float* wp = &Wlds[kk * 65 + ob];
            const float* ap = &Alds[kk * 65 + bb];
            float w0 = wp[0], w1 = wp[1], w2 = wp[2], w3 = wp[3];
#pragma unroll
            for (int j = 0; j < 4; ++j) {
                float av = ap[j];
                acc[0][j] = fmaf(w0, av, acc[0][j]);
                acc[1][j] = fmaf(w1, av, acc[1][j]);
                acc[2][j] = fmaf(w2, av, acc[2][j]);
                acc[3][j] = fmaf(w3, av, acc[3][j]);
            }
        }
    }
#pragma unroll
    for (int i = 0; i < 4; ++i)
#pragma unroll
        for (int j = 0; j < 4; ++j)
            C[(size_t)(b0 + bb + j) * 1408 + n0 + ob + i] = acc[i][j];
}

// ------------------------------------------------------------------
// per (head<7, b): sum 2 partials + bias + activations
__global__ __launch_bounds__(256) void k_headact(const float* __restrict__ C0,
                                                 const float* __restrict__ C1,
                                                 const float* __restrict__ bk, const float* __restrict__ bbeta,
                                                 const float* __restrict__ bg, const float* __restrict__ bs,
                                                 const float* __restrict__ bgam, const float* __restrict__ be,
                                                 const float* __restrict__ ba,
                                                 float* __restrict__ keys, float* __restrict__ knorm,
                                                 float* __restrict__ betaA, float* __restrict__ gA,
                                                 float* __restrict__ gammaA, float* __restrict__ sA,
                                                 float* __restrict__ eA, float* __restrict__ aA) {
    __shared__ float sk[64];
    __shared__ float s3[3];
    int blk = blockIdx.x;
    int i = blk >> 7, b = blk & 127;
    int q = threadIdx.x;
    float val = 0.f;
    if (q < 198) {
        float bv = (q < 64)   ? bk[(i << 6) + q]
                 : (q == 64)  ? bbeta[i]
                 : (q == 65)  ? bg[i]
                 : (q <= 68)  ? bs[i * 3 + q - 66]
                 : (q == 69)  ? bgam[i]
                 : (q < 134)  ? be[(i << 6) + q - 70]
                              : ba[(i << 6) + q - 134];
        size_t idx = (size_t)b * 1408 + i * 198 + q;
        val = C0[idx] + C1[idx] + bv;
    }
    if (q < 64) { keys[(size_t)(i * BSZ + b) * 64 + q] = val; sk[q] = val * val; }
    if (q >= 66 && q <= 68) s3[q - 66] = val;
    __syncthreads();
    if (q == 0) {
        float s = 0.f;
        for (int m2 = 0; m2 < 64; ++m2) s += sk[m2];
        knorm[i * BSZ + b] = sqrtf(s);
    }
    if (q == 64) betaA[i * BSZ + b] = softplusf_(val);
    if (q == 65) gA[i * BSZ + b] = sigmoidf_(val);
    if (q == 69) gammaA[i * BSZ + b] = 1.f + softplusf_(val);
    if (q == 66) {
        float mx = fmaxf(s3[0], fmaxf(s3[1], s3[2]));
        float e0 = expf(s3[0] - mx), e1 = expf(s3[1] - mx), e2 = expf(s3[2] - mx);
        float inv = 1.f / (e0 + e1 + e2);
        sA[(i * BSZ + b) * 3 + 0] = e0 * inv;
        sA[(i * BSZ + b) * 3 + 1] = e1 * inv;
        sA[(i * BSZ + b) * 3 + 2] = e2 * inv;
    }
    if (q >= 70 && q < 134)  eA[(size_t)(i * BSZ + b) * 64 + (q - 70)] = sigmoidf_(val);
    if (q >= 134 && q < 198) aA[(size_t)(i * BSZ + b) * 64 + (q - 134)] = tanhf(val);
}

// ------------------------------------------------------------------
// READ-ONLY sweep over pristine mem0. Reconstructs updated memory states in
// registers from write weights w1/w3/w5 + per-batch e/a vectors. Computes up
// to 2 sims on state `napply`, and a read-accumulate on state `read_state`.
// grid = B*N/64 blocks of 256; 16 lanes per row (float4 per lane)
__global__ __launch_bounds__(256) void k_pass2(const float* __restrict__ mem,
                                               const float* __restrict__ wbuf,
                                               const float* __restrict__ eA, const float* __restrict__ aA,
                                               const float* __restrict__ keys, const float* __restrict__ knorm,
                                               float* __restrict__ sims, float* __restrict__ r_out,
                                               int napply, int nsims, int sh0, int sh1,
                                               int read_state, int read_head, int read_idx) {
    __shared__ __align__(16) float rbuf[16][64];
    int t = threadIdx.x;
    int lane = t & 15, grp = t >> 4;
    int base = blockIdx.x * 64;       // 64 consecutive rows, same b
    int b = base >> 12;
    int m4 = lane * 4;
    float4 e1 = *(const float4*)(eA + (size_t)(1 * BSZ + b) * 64 + m4);
    float4 a1 = *(const float4*)(aA + (size_t)(1 * BSZ + b) * 64 + m4);
    float4 e3 = *(const float4*)(eA + (size_t)(3 * BSZ + b) * 64 + m4);
    float4 a3 = *(const float4*)(aA + (size_t)(3 * BSZ + b) * 64 + m4);
    float4 e5 = *(const float4*)(eA + (size_t)(5 * BSZ + b) * 64 + m4);
    float4 a5 = *(const float4*)(aA + (size_t)(5 * BSZ + b) * 64 + m4);
    float4 k0v = make_float4(0.f, 0.f, 0.f, 0.f), k1v = k0v;
    float kn0v = 0.f, kn1v = 0.f;
    if (nsims > 0) { k0v = *(const float4*)(keys + (size_t)(sh0 * BSZ + b) * 64 + m4); kn0v = knorm[sh0 * BSZ + b]; }
    if (nsims > 1) { k1v = *(const float4*)(keys + (size_t)(sh1 * BSZ + b) * 64 + m4); kn1v = knorm[sh1 * BSZ + b]; }
    const float* w1p = wbuf + (size_t)1 * BSZ * NN_;
    const float* w3p = wbuf + (size_t)3 * BSZ * NN_;
    const float* w5p = wbuf + (size_t)5 * BSZ * NN_;
    const float* wrp = (read_head >= 0) ? (wbuf + (size_t)read_head * BSZ * NN_) : nullptr;
    float* sim0 = sims + (size_t)sh0 * BSZ * NN_;
    float* sim1 = sims + (size_t)sh1 * BSZ * NN_;

    float4 racc = make_float4(0.f, 0.f, 0.f, 0.f);
    for (int it = 0; it < 4; ++it) {
        int row = base + it * 16 + grp;
        float4 m = *(const float4*)(mem + (size_t)row * 64 + m4);
        float4 mr = m;
        if (napply >= 1) {
            float w = w1p[row];
            m.x = m.x * (1.f - w * e1.x) + w * a1.x;
            m.y = m.y * (1.f - w * e1.y) + w * a1.y;
            m.z = m.z * (1.f - w * e1.z) + w * a1.z;
            m.w = m.w * (1.f - w * e1.w) + w * a1.w;
            if (read_state == 1) mr = m;
        }
        if (napply >= 2) {
            float w = w3p[row];
            m.x = m.x * (1.f - w * e3.x) + w * a3.x;
            m.y = m.y * (1.f - w * e3.y) + w * a3.y;
            m.z = m.z * (1.f - w * e3.z) + w * a3.z;
            m.w = m.w * (1.f - w * e3.w) + w * a3.w;
            if (read_state == 2) mr = m;
        }
        if (napply >= 3) {
            float w = w5p[row];
            m.x = m.x * (1.f - w * e5.x) + w * a5.x;
            m.y = m.y * (1.f - w * e5.y) + w * a5.y;
            m.z = m.z * (1.f - w * e5.z) + w * a5.z;
            m.w = m.w * (1.f - w * e5.w) + w * a5.w;
            if (read_state == 3) mr = m;
        }
        if (read_head >= 0) {
            float wr = wrp[row];
            racc.x = fmaf(wr, mr.x, racc.x);
            racc.y = fmaf(wr, mr.y, racc.y);
            racc.z = fmaf(wr, mr.z, racc.z);
            racc.w = fmaf(wr, mr.w, racc.w);
        }
        if (nsims > 0) {
            float d0 = m.x * k0v.x + m.y * k0v.y + m.z * k0v.z + m.w * k0v.w;
            float nn = m.x * m.x + m.y * m.y + m.z * m.z + m.w * m.w;
            float d1 = 0.f;
            if (nsims > 1) d1 = m.x * k1v.x + m.y * k1v.y + m.z * k1v.z + m.w * k1v.w;
#pragma unroll
            for (int off = 8; off >= 1; off >>= 1) {
                d0 += __shfl_xor(d0, off, 16);
                nn += __shfl_xor(nn, off, 16);
                if (nsims > 1) d1 += __shfl_xor(d1, off, 16);
            }
            if (lane == 0) {
                float nm = sqrtf(nn);
                sim0[row] = d0 / (nm * kn0v + EPSF);
                if (nsims > 1) sim1[row] = d1 / (nm * kn1v + EPSF);
            }
        }
    }
    if (read_head >= 0) {
        *(float4*)(&rbuf[grp][m4]) = racc;
        __syncthreads();
        if (t < 64) {
            float s = 0.f;
#pragma unroll
            for (int g2 = 0; g2 < 16; ++g2) s += rbuf[g2][t];
            atomicAdd(&r_out[(size_t)(read_idx * BSZ + b) * 64 + t], s);
        }
    }
}

// ------------------------------------------------------------------
// per (head, b): softmax(beta*sim) -> interpolate -> shift -> sharpen -> normalize
// 1024 threads, 4 elems/thread, wave-shuffle reductions (4 barriers total)
__global__ __launch_bounds__(1024) void k_weights(const float* __restrict__ sims,
                                                  const float* __restrict__ prev_w,
                                                  const float* __restrict__ betaA, const float* __restrict__ gA,
                                                  const float* __restrict__ gammaA, const float* __restrict__ sA,
                                                  float* __restrict__ wout_base, int head0) {
    __shared__ float wg[NN_];
    __shared__ float redm[16], reds[16], redp[16];
    int h = head0 + blockIdx.y, b = blockIdx.x;
    int hb = h * BSZ + b;
    float beta = betaA[hb], g = gA[hb], gamma = gammaA[hb];
    float s0 = sA[hb * 3 + 0], s1 = sA[hb * 3 + 1], s2 = sA[hb * 3 + 2];
    const float* sim = sims + (size_t)hb * NN_;
    const float* pw = prev_w + (size_t)hb * NN_;
    float* wout = wout_base + (size_t)hb * NN_;
    int t = threadIdx.x, wv = t >> 6, ln = t & 63;
    float tv[4];
    float lmax = -3.4e38f;
#pragma unroll
    for (int j = 0; j < 4; ++j) {
        float x = beta * sim[t + 1024 * j];
        tv[j] = x;
        lmax = fmaxf(lmax, x);
    }
#pragma unroll
    for (int off = 32; off >= 1; off >>= 1) lmax = fmaxf(lmax, __shfl_xor(lmax, off));
    if (ln == 0) redm[wv] = lmax;
    __syncthreads();
    float Mx = redm[0];
#pragma unroll
    for (int k = 1; k < 16; ++k) Mx = fmaxf(Mx, redm[k]);
    float lsum = 0.f;
#pragma unroll
    for (int j = 0; j < 4; ++j) { float ex = expf(tv[j] - Mx); tv[j] = ex; lsum += ex; }
#pragma unroll
    for (int off = 32; off >= 1; off >>= 1) lsum += __shfl_xor(lsum, off);
    if (ln == 0) reds[wv] = lsum;
    __syncthreads();
    float S = 0.f;
#pragma unroll
    for (int k = 0; k < 16; ++k) S += reds[k];
    float invS = 1.f / S;
#pragma unroll
    for (int j = 0; j < 4; ++j) {
        int n = t + 1024 * j;
        wg[n] = g * tv[j] * invS + (1.f - g) * pw[n];
    }
    __syncthreads();
    float lsum2 = 0.f;
#pragma unroll
    for (int j = 0; j < 4; ++j) {
        int n = t + 1024 * j;
        float wsft = s0 * wg[(n + 1) & (NN_ - 1)] + s1 * wg[n] + s2 * wg[(n - 1) & (NN_ - 1)];
        float wp = powf(wsft, gamma);
        tv[j] = wp;
        lsum2 += wp;
    }
#pragma unroll
    for (int off = 32; off >= 1; off >>= 1) lsum2 += __shfl_xor(lsum2, off);
    if (ln == 0) redp[wv] = lsum2;
    __syncthreads();
    float S2 = 0.f;
#pragma unroll
    for (int k = 0; k < 16; ++k) S2 += redp[k];
    float inv2 = 1.f / (S2 + EPSF);
#pragma unroll
    for (int j = 0; j < 4; ++j) wout[t + 1024 * j] = tv[j] * inv2;
}

// ------------------------------------------------------------------
// out[128,256] = sigmoid([hbuf|rbuf][128,768] @ W_out[256,768]^T + b_out)
// full-K (no atomics): grid = (4 n-tiles, 2 b-tiles)
__global__ __launch_bounds__(256) void k_out_full(const float* __restrict__ hbuf,
                                                  const float* __restrict__ rbuf,
                                                  const float* __restrict__ W_out,
                                                  const float* __restrict__ b_out,
                                                  float* __restrict__ out) {
    __shared__ float Alds[64 * 65];
    __shared__ float Wlds[64 * 65];
    int t = threadIdx.x;
    int n0 = blockIdx.x * 64;
    int b0 = blockIdx.y * 64;
    int ob = (t & 15) * 4;
    int bb = (t >> 4) * 4;
    float acc[4][4];
#pragma unroll
    for (int i = 0; i < 4; ++i)
#pragma unroll
        for (int j = 0; j < 4; ++j) acc[i][j] = 0.f;
    for (int k0 = 0; k0 < 768; k0 += 64) {
        __syncthreads();
        for (int i = 0; i < 4; ++i) {
            int f = t + 256 * i;
            int rb = f >> 4, kk = (f & 15) * 4;
            int k = k0 + kk;
            float4 v;
            if (k < 512) v = *(const float4*)(hbuf + ((b0 + rb) << 9) + k);
            else {
                int q = k - 512;
                v = *(const float4*)(rbuf + (((q >> 6) * BSZ + b0 + rb) << 6) + (q & 63));
            }
            Alds[(kk + 0) * 65 + rb] = v.x;
            Alds[(kk + 1) * 65 + rb] = v.y;
            Alds[(kk + 2) * 65 + rb] = v.z;
            Alds[(kk + 3) * 65 + rb] = v.w;
        }
        for (int i = 0; i < 4; ++i) {
            int f = t + 256 * i;
            int o = f >> 4, kk = (f & 15) * 4;
            float4 v = *(const float4*)(W_out + (size_t)(n0 + o) * 768 + k0 + kk);
            Wlds[(kk + 0) * 65 + o] = v.x;
            Wlds[(kk + 1) * 65 + o] = v.y;
            Wlds[(kk + 2) * 65 + o] = v.z;
            Wlds[(kk + 3) * 65 + o] = v.w;
        }
        __syncthreads();
        for (int kk = 0; kk < 64; ++kk) {
            const float* wp = &Wlds[kk * 65 + ob];
            const float* ap = &Alds[kk * 65 + bb];
            float w0 = wp[0], w1 = wp[1], w2 = wp[2], w3 = wp[3];
#pragma unroll
            for (int j = 0; j < 4; ++j) {
                float av = ap[j];
                acc[0][j] = fmaf(w0, av, acc[0][j]);
                acc[1][j] = fmaf(w1, av, acc[1][j]);
                acc[2][j] = fmaf(w2, av, acc[2][j]);
                acc[3][j] = fmaf(w3, av, acc[3][j]);
            }
        }
    }
#pragma unroll
    for (int i = 0; i < 4; ++i)
#pragma unroll
        for (int j = 0; j < 4; ++j)
            out[(size_t)(b0 + bb + j) * 256 + n0 + ob + i] = sigmoidf_(acc[i][j] + b_out[n0 + ob + i]);
}

// ------------------------------------------------------------------
extern "C" void kernel_launch(void* const* d_in, const int* in_sizes, int n_in,
                              void* d_out, int out_size, void* d_ws, size_t ws_size,
                              hipStream_t stream) {
    const float* in_data      = (const float*)d_in[0];
    const float* memory       = (const float*)d_in[1];   // READ-ONLY
    const float* h_prev       = (const float*)d_in[2];
    const float* c_prev       = (const float*)d_in[3];
    const float* prev_reads   = (const float*)d_in[4];
    const float* prev_weights = (const float*)d_in[5];
    const float* W_ih = (const float*)d_in[6];
    const float* b_ih = (const float*)d_in[7];
    const float* W_hh = (const float*)d_in[8];
    const float* b_hh = (const float*)d_in[9];
    const float* W_out = (const float*)d_in[10];
    const float* b_out = (const float*)d_in[11];
    const float* Wk   = (const float*)d_in[12];
    const float* bk   = (const float*)d_in[13];
    const float* Wbeta = (const float*)d_in[14];
    const float* bbeta = (const float*)d_in[15];
    const float* Wg   = (const float*)d_in[16];
    const float* bg   = (const float*)d_in[17];
    const float* Ws   = (const float*)d_in[18];
    const float* bs   = (const float*)d_in[19];
    const float* Wgam = (const float*)d_in[20];
    const float* bgam = (const float*)d_in[21];
    const float* We   = (const float*)d_in[22];
    const float* be   = (const float*)d_in[23];
    const float* Wa   = (const float*)d_in[24];
    const float* ba   = (const float*)d_in[25];

    float* ws = (float*)d_ws;
    // zero-init region: only rbuf (atomic read accumulator)
    size_t o_r      = 0;                          // [4,128,64] = 32768
    size_t zero_floats = 32768;                   // 128 KB
    size_t o_gatesP = zero_floats;                // 4 x [128,2048] = 1048576
    size_t o_cheadP = o_gatesP + 1048576;         // 2 x [128,1408] = 360448
    size_t o_c     = o_cheadP + 360448;           // [128,512]
    size_t o_h     = o_c + 65536;                 // [128,512]
    size_t o_keys  = o_h + 65536;                 // [7,128,64] = 57344
    size_t o_knorm = o_keys + 57344;              // [7,128] pad 1024
    size_t o_beta  = o_knorm + 1024;
    size_t o_g     = o_beta + 1024;
    size_t o_gamma = o_g + 1024;
    size_t o_s     = o_gamma + 1024;              // [7,128,3] pad 3072
    size_t o_e     = o_s + 3072;                  // [7,128,64] = 57344
    size_t o_a     = o_e + 57344;
    size_t o_sims  = o_a + 57344;                 // [7,128,4096] = 3670016
    size_t o_w     = o_sims + 3670016;            // [7,128,4096] = 3670016

    float* rbuf   = ws + o_r;
    float* gatesP = ws + o_gatesP;
    float* CheadP = ws + o_cheadP;
    float* cbuf   = ws + o_c;
    float* hbuf   = ws + o_h;
    float* keys   = ws + o_keys;
    float* knorm  = ws + o_knorm;
    float* betaA  = ws + o_beta;
    float* gA     = ws + o_g;
    float* gammaA = ws + o_gamma;
    float* sA     = ws + o_s;
    float* eA     = ws + o_e;
    float* aA     = ws + o_a;
    float* sims   = ws + o_sims;
    float* wbuf   = ws + o_w;

    hipMemsetAsync(d_ws, 0, zero_floats * sizeof(float), stream);

    // controller LSTM: split-K=4 partial GEMM (no atomics) + pointwise sum
    k_gemm_gates<<<dim3(32, 2, 4), 256, 0, stream>>>(in_data, prev_reads, h_prev, W_ih, W_hh, gatesP);
    k_lstm<<<256, 256, 0, stream>>>(gatesP, b_ih, b_hh, c_prev, cbuf, hbuf);

    // head params: split-K=2 partial GEMM over the 7 live heads (head 7 dead)
    k_gemm_head<<<dim3(22, 2, 2), 256, 0, stream>>>(cbuf, Wk, Wbeta, Wg, Ws, Wgam, We, Wa, CheadP);
    k_headact<<<896, 256, 0, stream>>>(CheadP, CheadP + (size_t)BSZ * 1408,
                                       bk, bbeta, bg, bs, bgam, be, ba,
                                       keys, knorm, betaA, gA, gammaA, sA, eA, aA);

    const int PB = BSZ * NN_ / 64;  // 8192 blocks per sweep
    // S0: sims heads 0,1 on mem0
    k_pass2<<<PB, 256, 0, stream>>>(memory, wbuf, eA, aA, keys, knorm, sims, rbuf,
                                    0, 2, 0, 1, -1, -1, 0);
    k_weights<<<dim3(128, 2), 1024, 0, stream>>>(sims, prev_weights, betaA, gA, gammaA, sA, wbuf, 0);
    // S1: sims heads 2,3 on mem1 (apply w1); r0 from mem0
    k_pass2<<<PB, 256, 0, stream>>>(memory, wbuf, eA, aA, keys, knorm, sims, rbuf,
                                    1, 2, 2, 3, 0, 0, 0);
    k_weights<<<dim3(128, 2), 1024, 0, stream>>>(sims, prev_weights, betaA, gA, gammaA, sA, wbuf, 2);
    // S2: sims heads 4,5 on mem2 (apply w1,w3); r2 from mem1
    k_pass2<<<PB, 256, 0, stream>>>(memory, wbuf, eA, aA, keys, knorm, sims, rbuf,
                                    2, 2, 4, 5, 1, 2, 1);
    k_weights<<<dim3(128, 2), 1024, 0, stream>>>(sims, prev_weights, betaA, gA, gammaA, sA, wbuf, 4);
    // S3: sim head 6 on mem3 (apply w1,w3,w5); r4 from mem2
    k_pass2<<<PB, 256, 0, stream>>>(memory, wbuf, eA, aA, keys, knorm, sims, rbuf,
                                    3, 1, 6, 6, 2, 4, 2);
    k_weights<<<dim3(128, 1), 1024, 0, stream>>>(sims, prev_weights, betaA, gA, gammaA, sA, wbuf, 6);
    // S4: r6 from mem3; head 7 dead
    k_pass2<<<PB, 256, 0, stream>>>(memory, wbuf, eA, aA, keys, knorm, sims, rbuf,
                                    3, 0, 0, 0, 3, 6, 3);

    // output layer (full-K GEMM fused with bias+sigmoid)
    k_out_full<<<dim3(4, 2), 256, 0, stream>>>(hbuf, rbuf, W_out, b_out, (float*)d_out);

    (void)in_sizes; (void)n_in; (void)out_size; (void)ws_size;
}